// Round 17
// baseline (40.538 us; speedup 1.0000x reference)
//
#include <hip/hip_runtime.h>
#include <hip/hip_bf16.h>

// Problem constants: B=32, T=256, N=1024 -> R = 8192 rows, K = N-1 = 1023 (padded to 1024)
// alpha = 0.5, b[m] = sqrt(m+1)-sqrt(m) = 1/(sqrt(m+1)+sqrt(m)), coef = sqrt(1023)/Gamma(1.5)
#define COEF 36.090511f
#define INV_COUNT (1.0f / 8388608.0f)   // 1 / (32*256*1024)

typedef __attribute__((ext_vector_type(4))) float f32x4;
typedef __attribute__((ext_vector_type(2))) unsigned long long u64x2;

typedef const __attribute__((address_space(1))) unsigned int* gas_ptr;
typedef __attribute__((address_space(3))) unsigned int* las_ptr;

__device__ __forceinline__ void load_lds16(const void* g, void* l) {
  __builtin_amdgcn_global_load_lds((gas_ptr)g, (las_ptr)l, 16, 0, 0);
}

// manual OCP e4m3fn decode (bias 7): exact
__device__ __forceinline__ float fp8_dec(unsigned int v) {
  const unsigned e = (v >> 3) & 0xF, m = v & 7;
  const int mant = e ? (8 + (int)m) : (int)m;
  const int ee = e ? (int)e : 1;
  float f = (float)mant * __int_as_float((ee + 117) << 23);  // mant * 2^(ee-10)
  return (v & 0x80) ? -f : f;
}

// prep blocks 0..8191: du8 rows, XCD-aligned map r = (b&7)*1024 + (b>>3).
// blocks 8192..8319: Mt8d = dedup'd Toeplitz B (8 tiles of 16KB, d = cb-kb).
__global__ void prep(const float* __restrict__ up, const float* __restrict__ utr,
                     unsigned char* __restrict__ du8, unsigned char* __restrict__ Mt8d,
                     float* __restrict__ dpart, float* __restrict__ ppart) {
  const int t = threadIdx.x;      // 256 threads
  if (blockIdx.x >= 8192) {
    const int g = (blockIdx.x - 8192) * 1024 + t * 4;   // byte index into 128KB tile set
    const int d = g >> 14;            // tile 0..7
    const int rem = g & 16383;
    const int ip = rem >> 7;          // i' 0..127
    const int j0 = rem & 127;         // j' byte
    float v[4];
#pragma unroll
    for (int e = 0; e < 4; e++) {
      int m = d * 128 + ip - (j0 + e);
      v[e] = 0.f;
      if (m >= 0) { float fm_ = (float)m; v[e] = 1.0f / (sqrtf(fm_ + 1.f) + sqrtf(fm_)); }
    }
    int w_ = __builtin_amdgcn_cvt_pk_fp8_f32(v[0], v[1], 0, false);
    w_ = __builtin_amdgcn_cvt_pk_fp8_f32(v[2], v[3], w_, true);
    *(unsigned int*)(Mt8d + g) = (unsigned int)w_;
    return;
  }

  const int r = ((blockIdx.x & 7) << 10) | (blockIdx.x >> 3);   // XCD-aligned row
  const int j0 = t * 4;
  const float* rowp = up + (size_t)r * 1024;

  f32x4 a = *(const f32x4*)(rowp + j0);
  f32x4 b = *(const f32x4*)(utr + (size_t)r * 1024 + j0);

  float a4 = __shfl_down(a[0], 1, 64);
  if ((t & 63) == 63 && t < 255) a4 = rowp[j0 + 4];

  float d0 = a[1] - a[0];
  float d1 = a[2] - a[1];
  float d2 = a[3] - a[2];
  float d3 = (t < 255) ? (a4 - a[3]) : 0.f;   // du[1023] = 0 pad

  int w_ = __builtin_amdgcn_cvt_pk_fp8_f32(d0, d1, 0, false);
  w_ = __builtin_amdgcn_cvt_pk_fp8_f32(d2, d3, w_, true);
  *(unsigned int*)(du8 + (size_t)r * 1024 + j0) = (unsigned int)w_;

  float e0 = a[0] - b[0], e1 = a[1] - b[1], e2 = a[2] - b[2], e3 = a[3] - b[3];
  float dsum = e0 * e0 + e1 * e1 + e2 * e2 + e3 * e3;

#pragma unroll
  for (int off = 32; off > 0; off >>= 1) dsum += __shfl_down(dsum, off, 64);
  __shared__ float ws4[4];
  const int lane = t & 63, w = t >> 6;
  if (lane == 0) ws4[w] = dsum;
  __syncthreads();
  if (t == 0) {
    dpart[r] = ws4[0] + ws4[1] + ws4[2] + ws4[3];
    ppart[r] = d0 * d0;   // physics residual at n=0: u_t = du[r,0], frac_lap[0] = 0
  }
}

// Y[r,i] = sum_j du[r,j] * b[i-j]; fused epilogue: resid = u_t - COEF*Y, psum += resid^2.
// fp8 GEMM: 64x128 tile, BK=128 bytes, 8 waves (32x32 wave tile), 1024 blocks.
// FULL double-buffer at 48KB (sA 2x8K + sB 2x16K) -> 3 blocks/CU = 24 waves/CU AND
// tile-k loads land a full compute-phase before their vmcnt(3) wait (latency hidden).
// XOR quad-swizzle, XCD map (bid&7), triangular cb uniform under 4-packs both orders.
__launch_bounds__(512, 6)
__global__ void gemm(const unsigned char* __restrict__ du8,
                     const unsigned char* __restrict__ Mt8d,
                     float* __restrict__ gpart,
                     const float* __restrict__ dpart, const float* __restrict__ ppart) {
  __shared__ unsigned char sA[2][8192];    // [64 rows][128 k-bytes], quad-swizzled
  __shared__ unsigned char sB[2][16384];   // [128 cols][128 k-bytes], quad-swizzled
  __shared__ float wsum[8];

  const int t = threadIdx.x;      // 512 threads = 8 waves
  const int w = t >> 6;
  const int lane = t & 63;

  const int bid = blockIdx.x;      // 0..1023
  const int xcd = bid & 7;
  const int local = bid >> 3;      // 0..127
  const int e = local & 1;
  const int j = local >> 1;        // 0..63
  const int h = (j < 32) ? (j & 7) : 7 - (j & 7);
  const int cb = e ? 7 - h : h;    // consecutive pairs AND +-32 j-pairs sum to 7
  const int r16 = (((j >> 3) & 3) << 2) | (((j >> 5) & 1) << 1) | e;   // bijective
  const int rb = xcd * 16 + r16;   // 0..127 (64-row tiles); XCD x owns rows [x*1024,+1024)
  const int row0 = rb * 64;
  const int col0 = cb * 128;
  const int nkb = cb + 1;          // K-blocks of 128 bytes (triangular skip)

  const f32x4 vzero = {0.f, 0.f, 0.f, 0.f};
  f32x4 acc[2][2];
#pragma unroll
  for (int i = 0; i < 2; i++)
#pragma unroll
    for (int jj = 0; jj < 2; jj++) acc[i][jj] = vzero;

  // staging: thread t covers (row = t>>3, phys quad = t&7); src quad = phys ^ (row&7)
  const int srow = t >> 3;                            // 0..63
  const int sq = ((t & 7) ^ (srow & 7)) * 16;         // pre-swizzled source byte col
  const unsigned char* gA0 = du8 + (size_t)(row0 + srow) * 1024 + sq;
  const unsigned char* gB0 = Mt8d + srow * 128 + sq;  // + d*16384 per iter

  auto stage = [&](int buf, int kb) {                 // 3 loads: A 8KB + B 16KB
    load_lds16(gA0 + kb * 128, (void*)&sA[buf][t * 16]);
    const size_t doff = (size_t)(cb - kb) * 16384;
#pragma unroll
    for (int l = 0; l < 2; l++)
      load_lds16(gB0 + doff + l * 64 * 128, (void*)&sB[buf][l * 8192 + t * 16]);
  };

  const int wm = w >> 2, wn = w & 3;     // wave tile: rows wm*32, cols wn*32
  const int frow = lane & 15;
  const int g4 = lane >> 4;              // lane's k-owner group 0..3

  auto compute = [&](int buf) {
#pragma unroll
    for (int p = 0; p < 2; p++) {
      const int lq = g4 * 2 + p;               // logical quad
      const int ph = lq ^ (frow & 7);          // physical quad (swizzle)
      u64x2 aV[2], bV[2];
#pragma unroll
      for (int fm = 0; fm < 2; fm++)
        aV[fm] = *(const u64x2*)&sA[buf][(wm * 32 + fm * 16 + frow) * 128 + ph * 16];
#pragma unroll
      for (int fn = 0; fn < 2; fn++)
        bV[fn] = *(const u64x2*)&sB[buf][(wn * 32 + fn * 16 + frow) * 128 + ph * 16];
#pragma unroll
      for (int fm = 0; fm < 2; fm++)
#pragma unroll
        for (int fn = 0; fn < 2; fn++) {
          acc[fm][fn] = __builtin_amdgcn_mfma_f32_16x16x32_fp8_fp8(
              (long long)aV[fm].x, (long long)bV[fn].x, acc[fm][fn], 0, 0, 0);
          acc[fm][fn] = __builtin_amdgcn_mfma_f32_16x16x32_fp8_fp8(
              (long long)aV[fm].y, (long long)bV[fn].y, acc[fm][fn], 0, 0, 0);
        }
    }
  };

  stage(0, 0);
  for (int kb = 0; kb < nkb; kb++) {
    // BARRIER A: all waves done computing kb-1 -> buf (kb+1)&1 free to overwrite
    asm volatile("" ::: "memory");
    __builtin_amdgcn_s_barrier();
    asm volatile("" ::: "memory");
    if (kb + 1 < nkb) {
      stage((kb + 1) & 1, kb + 1);                    // 3 loads stay in flight
      asm volatile("s_waitcnt vmcnt(3)" ::: "memory"); // tile-k loads (issued iter k-1) done
    } else {
      asm volatile("s_waitcnt vmcnt(0)" ::: "memory"); // last tile: drain
    }
    // BARRIER B: tile kb resident for all waves
    __builtin_amdgcn_s_barrier();
    asm volatile("" ::: "memory");
    compute(kb & 1);
  }

  // fused epilogue: C/D layout col = lane&15, row = (lane>>4)*4 + reg  [HW-verified].
  // du bytes from LAST A-tile in LDS: byte (rt,c) at rt*128 + ((c>>4)^(rt&7))*16 + (c&15).
  // Neighbor (c+1) via __shfl_down within 16-lane group; frow==15 reads explicitly.
  const int lastBuf = (nkb - 1) & 1;
  float psum = 0.f;
#pragma unroll
  for (int fm = 0; fm < 2; fm++) {
#pragma unroll
    for (int fn = 0; fn < 2; fn++) {
      const int c = wn * 32 + fn * 16 + frow;    // col within tile
      const int icol = col0 + c;                 // du index i; output position n = i+1
#pragma unroll
      for (int reg = 0; reg < 4; reg++) {
        const int rt = wm * 32 + fm * 16 + g4 * 4 + reg;   // row within tile (0..63)
        float dui = fp8_dec(sA[lastBuf][rt * 128 + (((c >> 4) ^ (rt & 7)) << 4) + (c & 15)]);
        float dnext = __shfl_down(dui, 1, 64);             // dui of (rt, c+1) for frow<15
        if (frow == 15) {
          if (c == 127) {                                  // tile edge: global byte (cb<7)
            dnext = (icol < 1022) ? fp8_dec(du8[(size_t)(row0 + rt) * 1024 + icol + 1]) : 0.f;
          } else {
            const int c1 = c + 1;
            dnext = fp8_dec(sA[lastBuf][rt * 128 + (((c1 >> 4) ^ (rt & 7)) << 4) + (c1 & 15)]);
          }
        }
        if (icol < 1023) {
          float frac = COEF * acc[fm][fn][reg];
          float ut = (icol == 1022) ? dui : 0.5f * (dui + dnext);
          float res = ut - frac;
          psum += res * res;
        }
      }
    }
  }

#pragma unroll
  for (int off = 32; off > 0; off >>= 1) psum += __shfl_down(psum, off, 64);
  if (lane == 0) wsum[w] = psum;

  // pre-reduce this block's 8-row slice of dpart/ppart (wave 0)
  float ds_ = 0.f, ps_ = 0.f;
  if (w == 0) {
    if (t < 8) { ds_ = dpart[bid * 8 + t]; ps_ = ppart[bid * 8 + t]; }
#pragma unroll
    for (int off = 4; off > 0; off >>= 1) {
      ds_ += __shfl_down(ds_, off, 64);
      ps_ += __shfl_down(ps_, off, 64);
    }
  }
  __syncthreads();
  if (t == 0) {
    float s = 0.f;
#pragma unroll
    for (int i = 0; i < 8; i++) s += wsum[i];
    gpart[bid] = s + ps_;
    gpart[1024 + bid] = ds_;
  }
}

// Single-block reduction of 2048 partials -> 3 outputs.
__global__ void finalize(const float* __restrict__ gpart, float* __restrict__ out) {
  const int t = threadIdx.x;    // 256 threads
  float ds = 0.f, ps = 0.f;
  for (int i = t; i < 1024; i += 256) { ps += gpart[i]; ds += gpart[1024 + i]; }

#pragma unroll
  for (int off = 32; off > 0; off >>= 1) {
    ds += __shfl_down(ds, off, 64);
    ps += __shfl_down(ps, off, 64);
  }
  __shared__ float sd[4], sp[4];
  const int lane = t & 63, w = t >> 6;
  if (lane == 0) { sd[w] = ds; sp[w] = ps; }
  __syncthreads();
  if (t == 0) {
    float data = (sd[0] + sd[1] + sd[2] + sd[3]) * INV_COUNT;
    float phys = (sp[0] + sp[1] + sp[2] + sp[3]) * INV_COUNT;
    out[0] = data + 0.1f * phys;
    out[1] = data;
    out[2] = phys;
  }
}

extern "C" void kernel_launch(void* const* d_in, const int* in_sizes, int n_in,
                              void* d_out, int out_size, void* d_ws, size_t ws_size,
                              hipStream_t stream) {
  const float* u_pred = (const float*)d_in[0];
  const float* u_true = (const float*)d_in[1];
  float* out = (float*)d_out;

  char* ws = (char*)d_ws;
  float* dpart = (float*)ws;                                    // 8192 floats (32 KiB)
  float* ppart = (float*)(ws + 32768);                          // 8192 floats (32 KiB)
  float* gpart = (float*)(ws + 65536);                          // 2048 floats (8 KiB)
  unsigned char* Mt8d = (unsigned char*)(ws + 131072);          // 8 tiles * 16 KiB = 128 KiB
  unsigned char* du8 = (unsigned char*)(ws + 131072 + 1048576); // 8192*1024 = 8 MiB

  prep<<<8320, 256, 0, stream>>>(u_pred, u_true, du8, Mt8d, dpart, ppart);
  gemm<<<1024, 512, 0, stream>>>(du8, Mt8d, gpart, dpart, ppart);
  finalize<<<1, 256, 0, stream>>>(gpart, out);
}

// Round 18
// 35.314 us; speedup vs baseline: 1.1479x; 1.1479x over previous
//
#include <hip/hip_runtime.h>
#include <hip/hip_bf16.h>

// Problem constants: B=32, T=256, N=1024 -> R = 8192 rows, K = N-1 = 1023 (padded to 1024)
// alpha = 0.5, b[m] = sqrt(m+1)-sqrt(m) = 1/(sqrt(m+1)+sqrt(m)), coef = sqrt(1023)/Gamma(1.5)
#define COEF 36.090511f
#define INV_COUNT (1.0f / 8388608.0f)   // 1 / (32*256*1024)

typedef __attribute__((ext_vector_type(4))) float f32x4;
typedef __attribute__((ext_vector_type(2))) unsigned long long u64x2;

typedef const __attribute__((address_space(1))) unsigned int* gas_ptr;
typedef __attribute__((address_space(3))) unsigned int* las_ptr;

__device__ __forceinline__ void load_lds16(const void* g, void* l) {
  __builtin_amdgcn_global_load_lds((gas_ptr)g, (las_ptr)l, 16, 0, 0);
}

// manual OCP e4m3fn decode (bias 7): exact
__device__ __forceinline__ float fp8_dec(unsigned int v) {
  const unsigned e = (v >> 3) & 0xF, m = v & 7;
  const int mant = e ? (8 + (int)m) : (int)m;
  const int ee = e ? (int)e : 1;
  float f = (float)mant * __int_as_float((ee + 117) << 23);  // mant * 2^(ee-10)
  return (v & 0x80) ? -f : f;
}

// prep blocks 0..8191: du8 rows, XCD-aligned map r = (b&7)*1024 + (b>>3).
// blocks 8192..8319: Mt8d = dedup'd Toeplitz B (8 tiles of 16KB, d = cb-kb).
__global__ void prep(const float* __restrict__ up, const float* __restrict__ utr,
                     unsigned char* __restrict__ du8, unsigned char* __restrict__ Mt8d,
                     float* __restrict__ dpart, float* __restrict__ ppart) {
  const int t = threadIdx.x;      // 256 threads
  if (blockIdx.x >= 8192) {
    const int g = (blockIdx.x - 8192) * 1024 + t * 4;   // byte index into 128KB tile set
    const int d = g >> 14;            // tile 0..7
    const int rem = g & 16383;
    const int ip = rem >> 7;          // i' 0..127
    const int j0 = rem & 127;         // j' byte
    float v[4];
#pragma unroll
    for (int e = 0; e < 4; e++) {
      int m = d * 128 + ip - (j0 + e);
      v[e] = 0.f;
      if (m >= 0) { float fm_ = (float)m; v[e] = 1.0f / (sqrtf(fm_ + 1.f) + sqrtf(fm_)); }
    }
    int w_ = __builtin_amdgcn_cvt_pk_fp8_f32(v[0], v[1], 0, false);
    w_ = __builtin_amdgcn_cvt_pk_fp8_f32(v[2], v[3], w_, true);
    *(unsigned int*)(Mt8d + g) = (unsigned int)w_;
    return;
  }

  const int r = ((blockIdx.x & 7) << 10) | (blockIdx.x >> 3);   // XCD-aligned row
  const int j0 = t * 4;
  const float* rowp = up + (size_t)r * 1024;

  f32x4 a = *(const f32x4*)(rowp + j0);
  f32x4 b = *(const f32x4*)(utr + (size_t)r * 1024 + j0);

  float a4 = __shfl_down(a[0], 1, 64);
  if ((t & 63) == 63 && t < 255) a4 = rowp[j0 + 4];

  float d0 = a[1] - a[0];
  float d1 = a[2] - a[1];
  float d2 = a[3] - a[2];
  float d3 = (t < 255) ? (a4 - a[3]) : 0.f;   // du[1023] = 0 pad

  int w_ = __builtin_amdgcn_cvt_pk_fp8_f32(d0, d1, 0, false);
  w_ = __builtin_amdgcn_cvt_pk_fp8_f32(d2, d3, w_, true);
  *(unsigned int*)(du8 + (size_t)r * 1024 + j0) = (unsigned int)w_;

  float e0 = a[0] - b[0], e1 = a[1] - b[1], e2 = a[2] - b[2], e3 = a[3] - b[3];
  float dsum = e0 * e0 + e1 * e1 + e2 * e2 + e3 * e3;

#pragma unroll
  for (int off = 32; off > 0; off >>= 1) dsum += __shfl_down(dsum, off, 64);
  __shared__ float ws4[4];
  const int lane = t & 63, w = t >> 6;
  if (lane == 0) ws4[w] = dsum;
  __syncthreads();
  if (t == 0) {
    dpart[r] = ws4[0] + ws4[1] + ws4[2] + ws4[3];
    ppart[r] = d0 * d0;   // physics residual at n=0: u_t = du[r,0], frac_lap[0] = 0
  }
}

// Y[r,i] = sum_j du[r,j] * b[i-j]; fused epilogue: resid = u_t - COEF*Y, psum += resid^2.
// fp8 GEMM: 64x128 tile, BK=128 bytes, 8 waves (32x32 wave tile), 1024 blocks, 32KB LDS
// -> 4 blocks/CU = 32 waves/CU (R16 geometry). R16's exposed B-latency fixed by
// REGISTER-prefetching B one iteration ahead (T14): vmcnt(1)/vmcnt(3) waits target
// loads issued a full compute-phase earlier. sB single-buffered; ds_write after barrier A.
__launch_bounds__(512, 8)
__global__ void gemm(const unsigned char* __restrict__ du8,
                     const unsigned char* __restrict__ Mt8d,
                     float* __restrict__ gpart,
                     const float* __restrict__ dpart, const float* __restrict__ ppart) {
  __shared__ unsigned char sA[2][8192];    // [64 rows][128 k-bytes], quad-swizzled
  __shared__ unsigned char sB[16384];      // [128 cols][128 k-bytes], single-buffered
  __shared__ float wsum[8];

  const int t = threadIdx.x;      // 512 threads = 8 waves
  const int w = t >> 6;
  const int lane = t & 63;

  const int bid = blockIdx.x;      // 0..1023
  const int xcd = bid & 7;
  const int local = bid >> 3;      // 0..127
  const int e = local & 1;
  const int j = local >> 1;        // 0..63
  const int h = (j < 32) ? (j & 7) : 7 - (j & 7);
  const int cb = e ? 7 - h : h;    // 2-packs and 4-packs of dispatch order sum uniform
  const int r16 = (((j >> 3) & 3) << 2) | (((j >> 5) & 1) << 1) | e;   // bijective
  const int rb = xcd * 16 + r16;   // 0..127; XCD x owns rows [x*1024, +1024)
  const int row0 = rb * 64;
  const int col0 = cb * 128;
  const int nkb = cb + 1;          // K-blocks of 128 bytes (triangular skip)

  const f32x4 vzero = {0.f, 0.f, 0.f, 0.f};
  f32x4 acc[2][2];
#pragma unroll
  for (int i = 0; i < 2; i++)
#pragma unroll
    for (int jj = 0; jj < 2; jj++) acc[i][jj] = vzero;

  // staging: thread t covers (row = t>>3, phys quad = t&7); src quad = phys ^ (row&7)
  const int srow = t >> 3;                            // 0..63
  const int sq = ((t & 7) ^ (srow & 7)) * 16;         // pre-swizzled source byte col
  const unsigned char* gA0 = du8 + (size_t)(row0 + srow) * 1024 + sq;
  const unsigned char* gB0 = Mt8d + srow * 128 + sq;  // + d*16384 per iter

  auto stageA = [&](int buf, int kb) {                // 1 load: 64x128 = 8KB
    load_lds16(gA0 + kb * 128, (void*)&sA[buf][t * 16]);
  };

  u64x2 bR0, bR1;                                     // B-tile reg prefetch (2x16B)
  auto ldB = [&](int kb) {                            // issue 2 global_load_dwordx4
    const size_t doff = (size_t)(cb - kb) * 16384;
    bR0 = *(const u64x2*)(gB0 + doff);
    bR1 = *(const u64x2*)(gB0 + doff + 8192);
  };
  auto writeB = [&]() {                               // 2 ds_write_b128 into sB
    *(u64x2*)&sB[t * 16] = bR0;
    *(u64x2*)&sB[8192 + t * 16] = bR1;
  };

  const int wm = w >> 2, wn = w & 3;     // wave tile: rows wm*32, cols wn*32
  const int frow = lane & 15;
  const int g4 = lane >> 4;              // lane's k-owner group 0..3

  auto compute = [&](int buf) {
#pragma unroll
    for (int p = 0; p < 2; p++) {
      const int lq = g4 * 2 + p;               // logical quad
      const int ph = lq ^ (frow & 7);          // physical quad (swizzle)
      u64x2 aV[2], bV[2];
#pragma unroll
      for (int fm = 0; fm < 2; fm++)
        aV[fm] = *(const u64x2*)&sA[buf][(wm * 32 + fm * 16 + frow) * 128 + ph * 16];
#pragma unroll
      for (int fn = 0; fn < 2; fn++)
        bV[fn] = *(const u64x2*)&sB[(wn * 32 + fn * 16 + frow) * 128 + ph * 16];
#pragma unroll
      for (int fm = 0; fm < 2; fm++)
#pragma unroll
        for (int fn = 0; fn < 2; fn++) {
          acc[fm][fn] = __builtin_amdgcn_mfma_f32_16x16x32_fp8_fp8(
              (long long)aV[fm].x, (long long)bV[fn].x, acc[fm][fn], 0, 0, 0);
          acc[fm][fn] = __builtin_amdgcn_mfma_f32_16x16x32_fp8_fp8(
              (long long)aV[fm].y, (long long)bV[fn].y, acc[fm][fn], 0, 0, 0);
        }
    }
  };

  // prologue: issue B(0) regs (older), then A(0) lds-direct (younger)
  ldB(0);
  stageA(0, 0);
  for (int kb = 0; kb < nkb; kb++) {
    // BARRIER A: compute(kb-1) done -> sB and sA[(kb+1)&1] free to overwrite
    asm volatile("" ::: "memory");
    __builtin_amdgcn_s_barrier();
    asm volatile("" ::: "memory");
    asm volatile("s_waitcnt vmcnt(1)" ::: "memory");   // B(kb) regs arrived (A(kb) pending)
    writeB();                                          // sB <- B(kb)
    if (kb + 1 < nkb) {
      ldB(kb + 1);                                     // issue B(kb+1) (2 loads, in flight)
      stageA((kb + 1) & 1, kb + 1);                    // issue A(kb+1) (1 load, in flight)
      asm volatile("s_waitcnt vmcnt(3)" ::: "memory"); // A(kb) arrived; 3 younger pending
    } else {
      asm volatile("s_waitcnt vmcnt(0)" ::: "memory"); // last tile: drain A(kb)
    }
    asm volatile("s_waitcnt lgkmcnt(0)" ::: "memory"); // this wave's ds_writes complete
    // BARRIER B: all waves' B-writes + A-tile resident
    __builtin_amdgcn_s_barrier();
    asm volatile("" ::: "memory");
    compute(kb & 1);
  }

  // fused epilogue: C/D layout col = lane&15, row = (lane>>4)*4 + reg  [HW-verified].
  // du bytes from LAST A-tile in LDS: byte (rt,c) at rt*128 + ((c>>4)^(rt&7))*16 + (c&15).
  // Neighbor (c+1) via __shfl_down within 16-lane group; frow==15 reads explicitly.
  const int lastBuf = (nkb - 1) & 1;
  float psum = 0.f;
#pragma unroll
  for (int fm = 0; fm < 2; fm++) {
#pragma unroll
    for (int fn = 0; fn < 2; fn++) {
      const int c = wn * 32 + fn * 16 + frow;    // col within tile
      const int icol = col0 + c;                 // du index i; output position n = i+1
#pragma unroll
      for (int reg = 0; reg < 4; reg++) {
        const int rt = wm * 32 + fm * 16 + g4 * 4 + reg;   // row within tile (0..63)
        float dui = fp8_dec(sA[lastBuf][rt * 128 + (((c >> 4) ^ (rt & 7)) << 4) + (c & 15)]);
        float dnext = __shfl_down(dui, 1, 64);             // dui of (rt, c+1) for frow<15
        if (frow == 15) {
          if (c == 127) {                                  // tile edge: global byte (cb<7)
            dnext = (icol < 1022) ? fp8_dec(du8[(size_t)(row0 + rt) * 1024 + icol + 1]) : 0.f;
          } else {
            const int c1 = c + 1;
            dnext = fp8_dec(sA[lastBuf][rt * 128 + (((c1 >> 4) ^ (rt & 7)) << 4) + (c1 & 15)]);
          }
        }
        if (icol < 1023) {
          float frac = COEF * acc[fm][fn][reg];
          float ut = (icol == 1022) ? dui : 0.5f * (dui + dnext);
          float res = ut - frac;
          psum += res * res;
        }
      }
    }
  }

#pragma unroll
  for (int off = 32; off > 0; off >>= 1) psum += __shfl_down(psum, off, 64);
  if (lane == 0) wsum[w] = psum;

  // pre-reduce this block's 8-row slice of dpart/ppart (wave 0)
  float ds_ = 0.f, ps_ = 0.f;
  if (w == 0) {
    if (t < 8) { ds_ = dpart[bid * 8 + t]; ps_ = ppart[bid * 8 + t]; }
#pragma unroll
    for (int off = 4; off > 0; off >>= 1) {
      ds_ += __shfl_down(ds_, off, 64);
      ps_ += __shfl_down(ps_, off, 64);
    }
  }
  __syncthreads();
  if (t == 0) {
    float s = 0.f;
#pragma unroll
    for (int i = 0; i < 8; i++) s += wsum[i];
    gpart[bid] = s + ps_;
    gpart[1024 + bid] = ds_;
  }
}

// Single-block reduction of 2048 partials -> 3 outputs.
__global__ void finalize(const float* __restrict__ gpart, float* __restrict__ out) {
  const int t = threadIdx.x;    // 256 threads
  float ds = 0.f, ps = 0.f;
  for (int i = t; i < 1024; i += 256) { ps += gpart[i]; ds += gpart[1024 + i]; }

#pragma unroll
  for (int off = 32; off > 0; off >>= 1) {
    ds += __shfl_down(ds, off, 64);
    ps += __shfl_down(ps, off, 64);
  }
  __shared__ float sd[4], sp[4];
  const int lane = t & 63, w = t >> 6;
  if (lane == 0) { sd[w] = ds; sp[w] = ps; }
  __syncthreads();
  if (t == 0) {
    float data = (sd[0] + sd[1] + sd[2] + sd[3]) * INV_COUNT;
    float phys = (sp[0] + sp[1] + sp[2] + sp[3]) * INV_COUNT;
    out[0] = data + 0.1f * phys;
    out[1] = data;
    out[2] = phys;
  }
}

extern "C" void kernel_launch(void* const* d_in, const int* in_sizes, int n_in,
                              void* d_out, int out_size, void* d_ws, size_t ws_size,
                              hipStream_t stream) {
  const float* u_pred = (const float*)d_in[0];
  const float* u_true = (const float*)d_in[1];
  float* out = (float*)d_out;

  char* ws = (char*)d_ws;
  float* dpart = (float*)ws;                                    // 8192 floats (32 KiB)
  float* ppart = (float*)(ws + 32768);                          // 8192 floats (32 KiB)
  float* gpart = (float*)(ws + 65536);                          // 2048 floats (8 KiB)
  unsigned char* Mt8d = (unsigned char*)(ws + 131072);          // 8 tiles * 16 KiB = 128 KiB
  unsigned char* du8 = (unsigned char*)(ws + 131072 + 1048576); // 8192*1024 = 8 MiB

  prep<<<8320, 256, 0, stream>>>(u_pred, u_true, du8, Mt8d, dpart, ppart);
  gemm<<<1024, 512, 0, stream>>>(du8, Mt8d, gpart, dpart, ppart);
  finalize<<<1, 256, 0, stream>>>(gpart, out);
}